// Round 1
// 102.807 us; speedup vs baseline: 1.0092x; 1.0092x over previous
//
#include <hip/hip_runtime.h>

// Linear interpolation: 8.4M samples vs 16384 sorted knots.
// R10: single self-contained kernel, ZERO workspace use.
//  - Records {f32 x, packed f16 y,s} and the u16 bucket->lo table are built
//    directly in LDS by each block. The per-bucket binary search of the old
//    build_tbl kernel is replaced by an O(1)-per-knot scatter: knot j covers
//    buckets (bucket(xp[j]), bucket(xp[j+1])] with value min(j, nk-2).
//    Exactly one knot writes each bucket (largest j with bucket(xp[j]) <= b-1),
//    so the table is bit-identical to the R9 binary-search table; records are
//    built with the same expressions -> output bit-identical to R9.
//  - Drops: build_tbl launch, recg/tbl global round-trip, all d_ws traffic.
//  - Hot loop (R8-proven window/select + depth-3 streaming pipeline) untouched.

#define NB 16256            // u16 table = 32512 B LDS
#define NKMAX 16384
#define PADR 4              // +INF pad records
#define NREC (NKMAX + PADR)

typedef float f32x4 __attribute__((ext_vector_type(4)));
typedef float f32x2 __attribute__((ext_vector_type(2)));

__device__ __forceinline__ int bucket_of(float v, float lo, float inv_w) {
    // Monotone in fp32; same expression everywhere.
    return (int)((v - lo) * inv_w);
}

__device__ __forceinline__ float pack_ys_f(float y, float s) {
    _Float16 hy = (_Float16)y, hs = (_Float16)s;
    unsigned short uy = __builtin_bit_cast(unsigned short, hy);
    unsigned short us = __builtin_bit_cast(unsigned short, hs);
    unsigned u = (unsigned)uy | ((unsigned)us << 16);
    return __builtin_bit_cast(float, u);
}

__device__ __forceinline__ float lerp_ys(float dx, float ysf) {
    unsigned u = __builtin_bit_cast(unsigned, ysf);
    float hy = (float)__builtin_bit_cast(_Float16, (unsigned short)(u & 0xffffu));
    float hs = (float)__builtin_bit_cast(_Float16, (unsigned short)(u >> 16));
    return fmaf(dx, hs, hy);
}

__global__ __launch_bounds__(1024) void interp(
        const f32x4* __restrict__ xs4, const float* __restrict__ xp,
        const float* __restrict__ yp, f32x4* __restrict__ out4, int n4, int nk) {
    __shared__ __align__(16) float srec[NREC * 2];   // 131104 B
    __shared__ unsigned short sT[NB];                // 32512 B

    float lo = xp[0];
    float inv_w = (float)NB / (xp[nk - 1] - lo);

    // ---- In-LDS build: records + bucket->lo scatter table ----
    {
        f32x2* sr2w = (f32x2*)srec;
        for (int i = threadIdx.x; i < nk + PADR; i += 1024) {
            float x, ysp;
            int b0 = 0, b1 = -1;                     // scatter range (empty by default)
            if (i < nk) {
                x = xp[i];
                float y = yp[i];
                float s = 0.0f;
                if (i < nk - 1) {
                    float xn = xp[i + 1];
                    s = (yp[i + 1] - y) / (xn - x);
                    b0 = bucket_of(x, lo, inv_w);
                    b1 = min(bucket_of(xn, lo, inv_w), NB - 1);
                }
                ysp = pack_ys_f(y, s);
            } else {                                 // pad: +INF knot, never selected
                x = __builtin_inff(); ysp = 0.0f;
            }
            f32x2 r; r.x = x; r.y = ysp;
            sr2w[i] = r;                             // ds_write_b64
            // Knot i answers buckets (bucket(x_i), bucket(x_{i+1})]: for b in that
            // range, i is the largest j with bucket(xp[j]) <= b-1. Unique writer
            // per bucket; <=3 trips (max knot gap 1.0 ~ 2 bucket widths).
            unsigned short v = (unsigned short)(i < nk - 2 ? i : nk - 2);
            for (int b = b0 + 1; b <= b1; b++) sT[b] = v;
        }
        if (threadIdx.x == 0) sT[0] = 0;             // no knot strictly left of bucket 0
    }
    __syncthreads();

    const f32x2* sr2 = (const f32x2*)srec;

    int tid = blockIdx.x * blockDim.x + threadIdx.x;
    int T = gridDim.x * blockDim.x;

    // Per-quad processing (R8-proven window/select logic, unchanged).
    auto process = [&](f32x4 xq) -> f32x4 {
        float x[4] = {xq.x, xq.y, xq.z, xq.w};
        int base[4];
        f32x2 r0[4], r1[4], r2[4], r3[4];
        #pragma unroll
        for (int k = 0; k < 4; k++) {
            int b = bucket_of(x[k], lo, inv_w);   // >= 0 since x >= xp[0]
            b = min(b, NB - 1);
            base[k] = (int)sT[b];
            r0[k] = sr2[base[k]];                 // adjacent pairs ->
            r1[k] = sr2[base[k] + 1];             //   2x ds_read2_b64
            r2[k] = sr2[base[k] + 2];
            r3[k] = sr2[base[k] + 3];
        }
        f32x4 res;
        #pragma unroll
        for (int k = 0; k < 4; k++) {
            float xk = x[k];
            float xi = r0[k].x, ys = r0[k].y;     // x_base <= xk guaranteed
            if (r1[k].x <= xk) { xi = r1[k].x; ys = r1[k].y; }
            if (r2[k].x <= xk) { xi = r2[k].x; ys = r2[k].y; }
            bool tail = (r3[k].x <= xk);
            if (tail) {
                // window exhausted (P ~ 2%): linear walk, exec-masked
                int j = base[k] + 3;
                while (srec[2 * (j + 1)] <= xk) j++;
                xi = srec[2 * j]; ys = srec[2 * j + 1];
            }
            res[k] = lerp_ys(xk - xi, ys);
        }
        return res;
    };

    if (n4 == 8 * T) {
        // Exact shape: 8 stages/thread, depth-3 software pipeline, fully
        // unrolled -> 3 streaming quads always in flight, evenly issued.
        f32x4 buf[8];
        #pragma unroll
        for (int s = 0; s < 3; s++)
            buf[s] = __builtin_nontemporal_load(&xs4[tid + s * T]);
        #pragma unroll
        for (int s = 0; s < 8; s++) {
            if (s + 3 < 8)
                buf[s + 3] = __builtin_nontemporal_load(&xs4[tid + (s + 3) * T]);
            f32x4 res = process(buf[s]);
            __builtin_nontemporal_store(res, &out4[tid + s * T]);
        }
    } else {
        // Generic fallback (any shape).
        for (int t = tid; t < n4; t += T) {
            f32x4 xq = __builtin_nontemporal_load(&xs4[t]);
            f32x4 res = process(xq);
            __builtin_nontemporal_store(res, &out4[t]);
        }
    }
}

extern "C" void kernel_launch(void* const* d_in, const int* in_sizes, int n_in,
                              void* d_out, int out_size, void* d_ws, size_t ws_size,
                              hipStream_t stream) {
    const float* xs = (const float*)d_in[0];
    const float* xp = (const float*)d_in[1];
    const float* yp = (const float*)d_in[2];
    int ns = in_sizes[0];
    int nk = in_sizes[1];
    (void)d_ws; (void)ws_size; (void)n_in; (void)out_size;

    int n4 = ns / 4;
    interp<<<256, 1024, 0, stream>>>((const f32x4*)xs, xp, yp,
                                     (f32x4*)d_out, n4, nk);
}

// Round 2
// 100.037 us; speedup vs baseline: 1.0371x; 1.0277x over previous
//
#include <hip/hip_runtime.h>

// Linear interpolation: 8.4M samples vs 16384 sorted knots.
// R11: R10 (single self-contained kernel, zero workspace) +
//  (a) broadcast-masked second window read: lanes with r1.x > xk (~85%)
//      gather r2/r3 from a UNIFORM address (record 0) -> LDS broadcast,
//      conflicts only among the ~15% of lanes that actually need the
//      second pair. Selects guarded by need1 so garbage is never accepted.
//  (b) depth-3 streaming prefetch hoisted BEFORE the LDS-build prologue,
//      hiding the first quads' HBM latency under the ~1.5us build.
// Window/select semantics otherwise identical to R8/R9/R10 (proven).

#define NB 16256            // u16 table = 32512 B LDS
#define NKMAX 16384
#define PADR 4              // +INF pad records
#define NREC (NKMAX + PADR)

typedef float f32x4 __attribute__((ext_vector_type(4)));
typedef float f32x2 __attribute__((ext_vector_type(2)));

__device__ __forceinline__ int bucket_of(float v, float lo, float inv_w) {
    // Monotone in fp32; same expression everywhere.
    return (int)((v - lo) * inv_w);
}

__device__ __forceinline__ float pack_ys_f(float y, float s) {
    _Float16 hy = (_Float16)y, hs = (_Float16)s;
    unsigned short uy = __builtin_bit_cast(unsigned short, hy);
    unsigned short us = __builtin_bit_cast(unsigned short, hs);
    unsigned u = (unsigned)uy | ((unsigned)us << 16);
    return __builtin_bit_cast(float, u);
}

__device__ __forceinline__ float lerp_ys(float dx, float ysf) {
    unsigned u = __builtin_bit_cast(unsigned, ysf);
    float hy = (float)__builtin_bit_cast(_Float16, (unsigned short)(u & 0xffffu));
    float hs = (float)__builtin_bit_cast(_Float16, (unsigned short)(u >> 16));
    return fmaf(dx, hs, hy);
}

__global__ __launch_bounds__(1024) void interp(
        const f32x4* __restrict__ xs4, const float* __restrict__ xp,
        const float* __restrict__ yp, f32x4* __restrict__ out4, int n4, int nk) {
    __shared__ __align__(16) float srec[NREC * 2];   // 131104 B
    __shared__ unsigned short sT[NB];                // 32512 B

    float lo = xp[0];
    float inv_w = (float)NB / (xp[nk - 1] - lo);

    int tid = blockIdx.x * blockDim.x + threadIdx.x;
    int T = gridDim.x * blockDim.x;
    bool exact = (n4 == 8 * T);

    // (b) Hoisted streaming prefetch: LDS-independent, in flight during build.
    f32x4 buf[8];
    if (exact) {
        #pragma unroll
        for (int s = 0; s < 3; s++)
            buf[s] = __builtin_nontemporal_load(&xs4[tid + s * T]);
    }

    // ---- In-LDS build: records + bucket->lo scatter table ----
    {
        f32x2* sr2w = (f32x2*)srec;
        for (int i = threadIdx.x; i < nk + PADR; i += 1024) {
            float x, ysp;
            int b0 = 0, b1 = -1;                     // scatter range (empty by default)
            if (i < nk) {
                x = xp[i];
                float y = yp[i];
                float s = 0.0f;
                if (i < nk - 1) {
                    float xn = xp[i + 1];
                    s = (yp[i + 1] - y) / (xn - x);
                    b0 = bucket_of(x, lo, inv_w);
                    b1 = min(bucket_of(xn, lo, inv_w), NB - 1);
                }
                ysp = pack_ys_f(y, s);
            } else {                                 // pad: +INF knot, never selected
                x = __builtin_inff(); ysp = 0.0f;
            }
            f32x2 r; r.x = x; r.y = ysp;
            sr2w[i] = r;                             // ds_write_b64
            // Knot i answers buckets (bucket(x_i), bucket(x_{i+1})]: unique
            // writer per bucket, <=3 trips (max knot gap ~2 bucket widths).
            unsigned short v = (unsigned short)(i < nk - 2 ? i : nk - 2);
            for (int b = b0 + 1; b <= b1; b++) sT[b] = v;
        }
        if (threadIdx.x == 0) sT[0] = 0;             // no knot strictly left of bucket 0
    }
    __syncthreads();

    const f32x2* sr2 = (const f32x2*)srec;

    // Per-quad processing. Window/select logic identical to R8-R10 except
    // the second pair (r2,r3) is gathered from a uniform broadcast address
    // for lanes that cannot accept it (need1 false); selects are guarded.
    auto process = [&](f32x4 xq) -> f32x4 {
        float x[4] = {xq.x, xq.y, xq.z, xq.w};
        int base[4];
        f32x2 r0[4], r1[4];
        #pragma unroll
        for (int k = 0; k < 4; k++) {
            int b = bucket_of(x[k], lo, inv_w);   // >= 0 since x >= xp[0]
            b = min(b, NB - 1);
            base[k] = (int)sT[b];
            r0[k] = sr2[base[k]];                 // adjacent pair ->
            r1[k] = sr2[base[k] + 1];             //   ds_read2_b64
        }
        bool need1[4];
        f32x2 r2[4], r3[4];
        #pragma unroll
        for (int k = 0; k < 4; k++) {
            need1[k] = (r1[k].x <= x[k]);         // ~15% of lanes
            int a2 = need1[k] ? base[k] + 2 : 0;  // broadcast addr when unneeded
            r2[k] = sr2[a2];                      // adjacent pair ->
            r3[k] = sr2[a2 + 1];                  //   ds_read2_b64 (mostly bcast)
        }
        f32x4 res;
        #pragma unroll
        for (int k = 0; k < 4; k++) {
            float xk = x[k];
            float xi = r0[k].x, ys = r0[k].y;     // x_base <= xk guaranteed
            if (need1[k])                  { xi = r1[k].x; ys = r1[k].y; }
            if (need1[k] && r2[k].x <= xk) { xi = r2[k].x; ys = r2[k].y; }
            bool tail = need1[k] && (r3[k].x <= xk);
            if (tail) {
                // window exhausted (P ~ 2%): linear walk, exec-masked
                int j = base[k] + 3;
                while (srec[2 * (j + 1)] <= xk) j++;
                xi = srec[2 * j]; ys = srec[2 * j + 1];
            }
            res[k] = lerp_ys(xk - xi, ys);
        }
        return res;
    };

    if (exact) {
        // Exact shape: 8 stages/thread, depth-3 software pipeline, fully
        // unrolled -> 3 streaming quads always in flight, evenly issued.
        #pragma unroll
        for (int s = 0; s < 8; s++) {
            if (s + 3 < 8)
                buf[s + 3] = __builtin_nontemporal_load(&xs4[tid + (s + 3) * T]);
            f32x4 res = process(buf[s]);
            __builtin_nontemporal_store(res, &out4[tid + s * T]);
        }
    } else {
        // Generic fallback (any shape).
        for (int t = tid; t < n4; t += T) {
            f32x4 xq = __builtin_nontemporal_load(&xs4[t]);
            f32x4 res = process(xq);
            __builtin_nontemporal_store(res, &out4[t]);
        }
    }
}

extern "C" void kernel_launch(void* const* d_in, const int* in_sizes, int n_in,
                              void* d_out, int out_size, void* d_ws, size_t ws_size,
                              hipStream_t stream) {
    const float* xs = (const float*)d_in[0];
    const float* xp = (const float*)d_in[1];
    const float* yp = (const float*)d_in[2];
    int ns = in_sizes[0];
    int nk = in_sizes[1];
    (void)d_ws; (void)ws_size; (void)n_in; (void)out_size;

    int n4 = ns / 4;
    interp<<<256, 1024, 0, stream>>>((const f32x4*)xs, xp, yp,
                                     (f32x4*)d_out, n4, nk);
}